// Round 18
// baseline (213.021 us; speedup 1.0000x reference)
//
#include <hip/hip_runtime.h>
#include <hip/hip_fp16.h>

// out[b, m, r] = x[b, ind[r,m]] * filters[r, ind[r,m]]
// rem = m*512+r; out flat = b*65536 + rem. Index set fixed across rows.
//
// map18 = map17 (wave-specialized producer/consumer, 1 row/block, grid=1024,
// idx-sorted entry table) with the R16 sync bug fixed:
//  - publishes are SINGLE-LANE (lane==0) __hip_atomic_fetch_add RELEASE
//    (R16 bug: per-lane atomicAdd inflated counters 64x/896x -> races).
//  - polls are __hip_atomic_load ACQUIRE (orders xbuf reads after the flag;
//    plain volatile let the compiler hoist gather reads above the poll).
// Waves 14,15 produce 8KB x-chunks into a 16KB ping-pong LDS buffer;
// waves 0..13 gather their chunk's sorted entries (fp32) and scatter fp16
// products into the 128KB outbuf; one barrier; coalesced sweep. Sweep
// stores are fire-and-forget -> drain overlaps the next block's produce.

constexpr int D_ROW = 128;
constexpr int D_COL = 512;
constexpr int D_ALL = D_ROW * D_COL;   // 65536
constexpr int BATCH = 1024;
constexpr int CHK   = 2048;            // floats per chunk (8 KB)
constexpr int NCH   = 32;
constexpr int NCONS = 14;              // consumer waves

// ---------------- build: counting sort by idx (proven in R10/R16) --------
__global__ void __launch_bounds__(1024)
k_hist(const int* __restrict__ ind, unsigned* __restrict__ offs) {
    const int rem = blockIdx.x * 1024 + threadIdx.x;
    const int m = rem >> 9, r = rem & 511;
    atomicAdd(&offs[ind[r * D_ROW + m]], 1u);
}

__global__ void __launch_bounds__(1024)
k_scan1(unsigned* __restrict__ offs, unsigned* __restrict__ part) {
    __shared__ unsigned s[1024];
    const int t = threadIdx.x;
    const int g = blockIdx.x * 1024 + t;
    const unsigned v = offs[g];
    s[t] = v;
    __syncthreads();
    #pragma unroll
    for (int d = 1; d < 1024; d <<= 1) {
        unsigned a = (t >= d) ? s[t - d] : 0u;
        __syncthreads();
        s[t] += a;
        __syncthreads();
    }
    offs[g] = s[t] - v;
    if (t == 1023) part[blockIdx.x] = s[t];
}

__global__ void __launch_bounds__(64)
k_scan2(unsigned* __restrict__ part) {
    __shared__ unsigned s[64];
    const int t = threadIdx.x;
    const unsigned v = part[t];
    s[t] = v;
    __syncthreads();
    #pragma unroll
    for (int d = 1; d < 64; d <<= 1) {
        unsigned a = (t >= d) ? s[t - d] : 0u;
        __syncthreads();
        s[t] += a;
        __syncthreads();
    }
    part[t] = s[t] - v;
}

__global__ void __launch_bounds__(1024)
k_scatter(const float* __restrict__ filters,
          const int*   __restrict__ ind,
          unsigned* __restrict__ offs,
          const unsigned* __restrict__ part,
          unsigned* __restrict__ irb,
          unsigned short* __restrict__ wb) {
    const int rem = blockIdx.x * 1024 + threadIdx.x;
    const int m = rem >> 9, r = rem & 511;
    const int idx = ind[r * D_ROW + m];
    const float w = filters[(size_t)r * D_ALL + idx];
    const unsigned pos = part[idx >> 10] + atomicAdd(&offs[idx], 1u);
    irb[pos] = ((unsigned)idx << 16) | (unsigned)rem;
    wb[pos]  = __half_as_ushort(__float2half_rn(w));
}

// ---------------- main ----------------
__global__ void __launch_bounds__(1024)
map18(const float* __restrict__ x,
      const unsigned* __restrict__ part,       // 64 group prefixes
      const unsigned* __restrict__ irb,
      const unsigned short* __restrict__ wb,
      float* __restrict__ out) {
    __shared__ float    xbuf[2][CHK];          // 16 KB ping-pong
    __shared__ __half   outbuf[D_ALL];         // 128 KB
    __shared__ unsigned ready[2];              // chunks published per parity
    __shared__ unsigned done2[2];              // per-wave completions per parity
    __shared__ unsigned chb[NCH + 1];          // chunk entry boundaries

    const int t    = threadIdx.x;
    const int wv   = t >> 6;                   // wave 0..15
    const int lane = t & 63;
    const int b    = blockIdx.x;

    if (t < 2)   { ready[t] = 0u; done2[t] = 0u; }
    if (t < NCH) chb[t] = part[2 * t];
    if (t == NCH) chb[NCH] = (unsigned)D_ALL;
    __syncthreads();

    const float* xrow = x + ((size_t)b << 16);

    if (wv >= NCONS) {
        // ---- producer: wv==14 -> even chunks (parity 0), 15 -> odd ----
        const int p = wv - NCONS;
        for (int i = 0; i < NCH / 2; ++i) {
            const int c = 2 * i + p;
            if (i > 0) {   // xbuf[p] still held by chunk c-2 consumers?
                while (__hip_atomic_load(&done2[p], __ATOMIC_ACQUIRE,
                                         __HIP_MEMORY_SCOPE_WORKGROUP)
                       < (unsigned)(NCONS * i))
                    __builtin_amdgcn_s_sleep(2);
            }
            const float4* src = reinterpret_cast<const float4*>(xrow + c * CHK);
            float4 f0 = src[lane];
            float4 f1 = src[64 + lane];
            float4 f2 = src[128 + lane];
            float4 f3 = src[192 + lane];
            float4 f4 = src[256 + lane];
            float4 f5 = src[320 + lane];
            float4 f6 = src[384 + lane];
            float4 f7 = src[448 + lane];
            float4* dst = reinterpret_cast<float4*>(xbuf[p]);
            dst[lane]       = f0;
            dst[64 + lane]  = f1;
            dst[128 + lane] = f2;
            dst[192 + lane] = f3;
            dst[256 + lane] = f4;
            dst[320 + lane] = f5;
            dst[384 + lane] = f6;
            dst[448 + lane] = f7;
            if (lane == 0)   // RELEASE: orders this wave's ds_writes first
                __hip_atomic_fetch_add(&ready[p], 1u, __ATOMIC_RELEASE,
                                       __HIP_MEMORY_SCOPE_WORKGROUP);
        }
    } else {
        // ---- consumer: waves 0..13 ----
        for (int c = 0; c < NCH; ++c) {
            const unsigned tgt = (unsigned)(c / 2 + 1);
            while (__hip_atomic_load(&ready[c & 1], __ATOMIC_ACQUIRE,
                                     __HIP_MEMORY_SCOPE_WORKGROUP) < tgt)
                __builtin_amdgcn_s_sleep(2);
            const int cs = (int)chb[c], ce = (int)chb[c + 1];
            const float* xb = xbuf[c & 1];
            for (int e = cs + wv * 64 + lane; e < ce; e += NCONS * 64) {
                const unsigned ir = irb[e];
                const float w = __half2float(__ushort_as_half(wb[e]));
                const float xv = xb[(ir >> 16) & (CHK - 1)];
                outbuf[ir & 0xffffu] = __float2half_rn(xv * w);
            }
            if (lane == 0)   // RELEASE: orders this wave's xbuf reads/outbuf writes
                __hip_atomic_fetch_add(&done2[c & 1], 1u, __ATOMIC_RELEASE,
                                       __HIP_MEMORY_SCOPE_WORKGROUP);
        }
    }
    __syncthreads();   // outbuf complete (rem is a permutation)

    // ---- sweep: fp16 outbuf -> fp32 out, fully coalesced ----
    float* ob = out + ((size_t)b << 16);
    #pragma unroll
    for (int i = 0; i < 8; ++i) {
        uint4 u = *reinterpret_cast<const uint4*>(&outbuf[i * 8192 + t * 8]);
        __half2 a = *reinterpret_cast<__half2*>(&u.x);
        __half2 bb = *reinterpret_cast<__half2*>(&u.y);
        __half2 c = *reinterpret_cast<__half2*>(&u.z);
        __half2 d = *reinterpret_cast<__half2*>(&u.w);
        float4 f0, f1;
        f0.x = __half2float(a.x);  f0.y = __half2float(a.y);
        f0.z = __half2float(bb.x); f0.w = __half2float(bb.y);
        f1.x = __half2float(c.x);  f1.y = __half2float(c.y);
        f1.z = __half2float(d.x);  f1.w = __half2float(d.y);
        *reinterpret_cast<float4*>(ob + i * 8192 + t * 8)     = f0;
        *reinterpret_cast<float4*>(ob + i * 8192 + t * 8 + 4) = f1;
    }
}

// ---------------- fallback: map13 (116us known-good) ----------------
__global__ void __launch_bounds__(256)
build_pk(const float* __restrict__ filters,
         const int*   __restrict__ ind,
         unsigned* __restrict__ pk) {
    int t = blockIdx.x * 256 + threadIdx.x;
    if (t >= D_ALL) return;
    int m = t >> 9, r = t & 511;
    int idx = ind[r * D_ROW + m];
    __half hw = __float2half_rn(filters[(size_t)r * D_ALL + idx]);
    pk[t] = ((unsigned)__half_as_ushort(hw) << 16) | (unsigned)idx;
}

__device__ __forceinline__ float map_one(const __half* xs, unsigned p) {
    return __half2float(xs[p & 0xffffu]) *
           __half2float(__ushort_as_half((unsigned short)(p >> 16)));
}
__device__ __forceinline__ unsigned h2bits(float a, float b) {
    __half2 h = __floats2half2_rn(a, b);
    return *reinterpret_cast<unsigned*>(&h);
}
__device__ __forceinline__ void lds_barrier() {
    asm volatile("s_waitcnt lgkmcnt(0)" ::: "memory");
    __builtin_amdgcn_s_barrier();
}

__global__ void __launch_bounds__(1024)
map13(const float* __restrict__ x,
      const uint4* __restrict__ pk4,
      float* __restrict__ out) {
    __shared__ __half xs[D_ALL];
    const int t = threadIdx.x;
    const int b = blockIdx.x;
    const float4* src = reinterpret_cast<const float4*>(x + ((size_t)b << 16));
    #pragma unroll
    for (int i = 0; i < 8; ++i) {
        float4 v0 = src[i * 2048 + t * 2];
        float4 v1 = src[i * 2048 + t * 2 + 1];
        uint4 u;
        u.x = h2bits(v0.x, v0.y);
        u.y = h2bits(v0.z, v0.w);
        u.z = h2bits(v1.x, v1.y);
        u.w = h2bits(v1.z, v1.w);
        *reinterpret_cast<uint4*>(xs + (size_t)(i * 2048 + t * 2) * 4) = u;
    }
    lds_barrier();
    float* ob = out + ((size_t)b << 16);
    uint4 p = pk4[t];
    #pragma unroll 4
    for (int j = 0; j < 16; ++j) {
        uint4 cur = p;
        if (j + 1 < 16) p = pk4[(j + 1) * 1024 + t];
        float4 r;
        r.x = map_one(xs, cur.x);
        r.y = map_one(xs, cur.y);
        r.z = map_one(xs, cur.z);
        r.w = map_one(xs, cur.w);
        *reinterpret_cast<float4*>(ob + j * 4096 + t * 4) = r;
    }
}

__global__ void __launch_bounds__(256)
map_kernel_nows(const float* __restrict__ x,
                const float* __restrict__ filters,
                const int*   __restrict__ ind,
                float*       __restrict__ out) {
    size_t o = (size_t)blockIdx.x * 256 + threadIdx.x;
    if (o >= (size_t)BATCH * D_ALL) return;
    unsigned b = (unsigned)(o >> 16);
    unsigned rem = (unsigned)(o & 65535u);
    unsigned m = rem >> 9, r = rem & 511u;
    int idx = ind[r * D_ROW + m];
    out[o] = x[((size_t)b << 16) + idx] * filters[(size_t)r * D_ALL + idx];
}

extern "C" void kernel_launch(void* const* d_in, const int* in_sizes, int n_in,
                              void* d_out, int out_size, void* d_ws, size_t ws_size,
                              hipStream_t stream) {
    const float* x       = (const float*)d_in[0];
    const float* filters = (const float*)d_in[1];
    const int*   ind     = (const int*)d_in[2];
    float*       out     = (float*)d_out;

    // ws layout for map18
    const size_t off_offs = 0;                               // u32[65536]
    const size_t off_part = off_offs + (size_t)D_ALL * 4;    // u32[64] (+pad 256)
    const size_t off_ir   = off_part + 256;                  // u32[65536]
    const size_t off_w    = off_ir + (size_t)D_ALL * 4;      // u16[65536]
    const size_t need18   = off_w + (size_t)D_ALL * 2;       // ~896 KB
    const size_t need13   = (size_t)D_ALL * sizeof(unsigned);

    if (ws_size >= need18) {
        unsigned* offs = (unsigned*)((char*)d_ws + off_offs);
        unsigned* part = (unsigned*)((char*)d_ws + off_part);
        unsigned* irb  = (unsigned*)((char*)d_ws + off_ir);
        unsigned short* wb = (unsigned short*)((char*)d_ws + off_w);
        hipMemsetAsync(offs, 0, (size_t)D_ALL * 4, stream);
        k_hist   <<<D_ALL / 1024, 1024, 0, stream>>>(ind, offs);
        k_scan1  <<<64, 1024, 0, stream>>>(offs, part);
        k_scan2  <<<1, 64, 0, stream>>>(part);
        k_scatter<<<D_ALL / 1024, 1024, 0, stream>>>(filters, ind, offs, part, irb, wb);
        map18<<<BATCH, 1024, 0, stream>>>(x, part, irb, wb, out);
    } else if (ws_size >= need13) {
        unsigned* pk = (unsigned*)d_ws;
        build_pk<<<D_ALL / 256, 256, 0, stream>>>(filters, ind, pk);
        map13<<<BATCH, 1024, 0, stream>>>(
            x, reinterpret_cast<const uint4*>(pk), out);
    } else {
        map_kernel_nows<<<(BATCH * (size_t)D_ALL) / 256, 256, 0, stream>>>(
            x, filters, ind, out);
    }
}

// Round 19
// 116.083 us; speedup vs baseline: 1.8351x; 1.8351x over previous
//
#include <hip/hip_runtime.h>
#include <hip/hip_fp16.h>

// out[b, m, r] = x[b, ind[r,m]] * filters[r, ind[r,m]]
// rem = m*512+r; out flat = b*65536 + rem.
//
// FINAL: map13 (116us, best of 18 rounds). One batch row per block,
// grid=1024. Stage row as fp16 into 128KB LDS (coalesced float4 -> cvt ->
// ds_write_b128), LDS-only barrier, then 64 outputs/thread: packed pk table
// (fp16 w | idx) streamed 1 group ahead, LDS gathers, coalesced fp32 stores.
// Inter-block overlap supplies read/write concurrency: block n+1's stage
// loads issue from fresh wave slots while block n's stores drain (no
// vmcnt coupling across blocks). Tested-and-rejected alternatives:
//  - in-block prefetch any ordering (R7/R8: +-2us; same-wave vmcnt couples)
//  - 2 blocks/CU half-rows (R11/R12: neutral; latency not occupancy-bound)
//  - sorted global gather (R10: 152us; scattered-VMEM issue cost)
//  - >64 live VGPRs in 1024-thread blocks (R3/4/6/15: allocator spills)
//  - wave-specialized producer/consumer (R17: 213us; producer BW + poll cost)

constexpr int D_ROW = 128;
constexpr int D_COL = 512;
constexpr int D_ALL = D_ROW * D_COL;   // 65536
constexpr int BATCH = 1024;

// pk[m*512+r] = (fp16bits(filters[r, ind[r,m]]) << 16) | ind[r,m]
__global__ void __launch_bounds__(256)
build_pk(const float* __restrict__ filters,
         const int*   __restrict__ ind,
         unsigned* __restrict__ pk) {
    int t = blockIdx.x * 256 + threadIdx.x;
    if (t >= D_ALL) return;
    int m = t >> 9, r = t & 511;
    int idx = ind[r * D_ROW + m];
    __half hw = __float2half_rn(filters[(size_t)r * D_ALL + idx]);
    pk[t] = ((unsigned)__half_as_ushort(hw) << 16) | (unsigned)idx;
}

__device__ __forceinline__ float map_one(const __half* xs, unsigned p) {
    return __half2float(xs[p & 0xffffu]) *
           __half2float(__ushort_as_half((unsigned short)(p >> 16)));
}
__device__ __forceinline__ unsigned h2bits(float a, float b) {
    __half2 h = __floats2half2_rn(a, b);
    return *reinterpret_cast<unsigned*>(&h);
}
__device__ __forceinline__ void lds_barrier() {
    asm volatile("s_waitcnt lgkmcnt(0)" ::: "memory");
    __builtin_amdgcn_s_barrier();
}

__global__ void __launch_bounds__(1024)
map13(const float* __restrict__ x,
      const uint4* __restrict__ pk4,    // pk4[j*1024 + t]
      float* __restrict__ out) {
    __shared__ __half xs[D_ALL];        // 128 KB: full row as fp16
    const int t = threadIdx.x;          // 0..1023
    const int b = blockIdx.x;           // one batch row per block

    // ---- stage: x row -> fp16 LDS (compiler pipelines the 16 loads) ----
    const float4* src = reinterpret_cast<const float4*>(x + ((size_t)b << 16));
    #pragma unroll
    for (int i = 0; i < 8; ++i) {
        float4 v0 = src[i * 2048 + t * 2];
        float4 v1 = src[i * 2048 + t * 2 + 1];
        uint4 u;
        u.x = h2bits(v0.x, v0.y);
        u.y = h2bits(v0.z, v0.w);
        u.z = h2bits(v1.x, v1.y);
        u.w = h2bits(v1.z, v1.w);
        *reinterpret_cast<uint4*>(xs + (size_t)(i * 2048 + t * 2) * 4) = u;
    }
    lds_barrier();

    // ---- compute: 64 outputs/thread; pk streamed 1 group ahead ----
    float* ob = out + ((size_t)b << 16);
    uint4 p = pk4[t];
    #pragma unroll 4
    for (int j = 0; j < 16; ++j) {
        uint4 cur = p;
        if (j + 1 < 16) p = pk4[(j + 1) * 1024 + t];
        float4 r;
        r.x = map_one(xs, cur.x);
        r.y = map_one(xs, cur.y);
        r.z = map_one(xs, cur.z);
        r.w = map_one(xs, cur.w);
        *reinterpret_cast<float4*>(ob + j * 4096 + t * 4) = r;
    }
}

// ---------------- fallback: direct gather (correct, slow) ----------------
__global__ void __launch_bounds__(256)
map_kernel_nows(const float* __restrict__ x,
                const float* __restrict__ filters,
                const int*   __restrict__ ind,
                float*       __restrict__ out) {
    size_t o = (size_t)blockIdx.x * 256 + threadIdx.x;
    if (o >= (size_t)BATCH * D_ALL) return;
    unsigned b = (unsigned)(o >> 16);
    unsigned rem = (unsigned)(o & 65535u);
    unsigned m = rem >> 9, r = rem & 511u;
    int idx = ind[r * D_ROW + m];
    out[o] = x[((size_t)b << 16) + idx] * filters[(size_t)r * D_ALL + idx];
}

extern "C" void kernel_launch(void* const* d_in, const int* in_sizes, int n_in,
                              void* d_out, int out_size, void* d_ws, size_t ws_size,
                              hipStream_t stream) {
    const float* x       = (const float*)d_in[0];
    const float* filters = (const float*)d_in[1];
    const int*   ind     = (const int*)d_in[2];
    float*       out     = (float*)d_out;

    const size_t need = (size_t)D_ALL * sizeof(unsigned);   // 256 KB
    if (ws_size >= need) {
        unsigned* pk = (unsigned*)d_ws;
        build_pk<<<D_ALL / 256, 256, 0, stream>>>(filters, ind, pk);
        map13<<<BATCH, 1024, 0, stream>>>(
            x, reinterpret_cast<const uint4*>(pk), out);
    } else {
        map_kernel_nows<<<(BATCH * (size_t)D_ALL) / 256, 256, 0, stream>>>(
            x, filters, ind, out);
    }
}